// Round 6
// baseline (497.695 us; speedup 1.0000x reference)
//
#include <hip/hip_runtime.h>
#include <hip/hip_bf16.h>
#include <math.h>

#define NN 100000
#define NE 1600000

#define NCB 391             // coarse buckets of 256 nodes
#define EB  8192            // edges per scatter block
#define SCT 512             // scatter block threads
#define HBK 128             // histogram blocks

typedef __attribute__((ext_vector_type(8))) short short8;
typedef __attribute__((ext_vector_type(4))) float f32x4;

// ---------- bf16 helpers ----------
__device__ __forceinline__ unsigned short f2bf(float f) {
  union { float f; unsigned int i; } v; v.f = f;
  unsigned int i = v.i;
  unsigned int r = (i + 0x7FFFu + ((i >> 16) & 1u)) >> 16;   // RNE
  return (unsigned short)r;
}
__device__ __forceinline__ float bflo(unsigned int u) {
  union { unsigned int i; float f; } v; v.i = u << 16; return v.f;
}
__device__ __forceinline__ float bfhi(unsigned int u) {
  union { unsigned int i; float f; } v; v.i = u & 0xFFFF0000u; return v.f;
}
__device__ __forceinline__ float bf1(unsigned short u) {
  union { unsigned int i; float f; } v; v.i = ((unsigned int)u) << 16; return v.f;
}

// ---------------- CSR build: hierarchical counting sort ----------------
// A: per-block bucket histograms -> partials (no global atomics, no memset)
__global__ __launch_bounds__(512) void k_chist(const int* __restrict__ dst,
                                               int* __restrict__ part) {
  __shared__ int h[NCB];
  for (int i = threadIdx.x; i < NCB; i += 512) h[i] = 0;
  __syncthreads();
  int stride = HBK * 512;
  for (int e = blockIdx.x * 512 + threadIdx.x; e < NE; e += stride) {
    int d = dst[e];
    d = d < 0 ? 0 : (d >= NN ? NN - 1 : d);
    atomicAdd(&h[d >> 8], 1);
  }
  __syncthreads();
  for (int i = threadIdx.x; i < NCB; i += 512) part[blockIdx.x * NCB + i] = h[i];
}

// B: reduce partials + exclusive scan; zeroes ccur; seeds csroff[NN]
__global__ __launch_bounds__(512) void k_cscan(const int* __restrict__ part,
                                               int* __restrict__ cboff,
                                               int* __restrict__ ccur,
                                               int* __restrict__ csroff) {
  __shared__ int sd[512];
  int t = threadIdx.x;
  int v = 0;
  if (t < NCB) {
    int s0 = 0, s1 = 0, s2 = 0, s3 = 0;
    #pragma unroll 4
    for (int k = 0; k < HBK; k += 4) {
      s0 += part[(k + 0) * NCB + t];
      s1 += part[(k + 1) * NCB + t];
      s2 += part[(k + 2) * NCB + t];
      s3 += part[(k + 3) * NCB + t];
    }
    v = (s0 + s1) + (s2 + s3);
    ccur[t] = 0;
  }
  sd[t] = v;
  __syncthreads();
  for (int st = 1; st < 512; st <<= 1) {
    int x = (t >= st) ? sd[t - st] : 0;
    __syncthreads();
    sd[t] += x;
    __syncthreads();
  }
  if (t < NCB) cboff[t] = sd[t] - v;
  if (t == NCB - 1) { cboff[NCB] = sd[t]; csroff[NN] = sd[t]; }
}

// C: scatter into coarse-bucket-sorted ebuf. Payload staged in LDS (no scratch
// spill — round-3's k_bscatter showed VGPR=4 + per-thread arrays = scratch).
__global__ __launch_bounds__(SCT) void k_cscatter(
    const int* __restrict__ src, const int* __restrict__ dst,
    const int* __restrict__ cboff, int* __restrict__ ccur,
    unsigned int* __restrict__ ebuf) {
  __shared__ int lh[NCB];
  __shared__ unsigned int sRank[EB];   // (cb<<13)|r, 0xFFFFFFFF = invalid
  __shared__ unsigned int sPay[EB];    // (dst&255)<<17 | src
  int t = threadIdx.x;
  int base = blockIdx.x * EB;
  for (int i = t; i < NCB; i += SCT) lh[i] = 0;
  __syncthreads();
  #pragma unroll
  for (int i = 0; i < EB / SCT; i++) {
    int idx = i * SCT + t;
    int e = base + idx;
    unsigned int rk = 0xFFFFFFFFu, pv = 0;
    if (e < NE) {
      int d = dst[e];
      d = d < 0 ? 0 : (d >= NN ? NN - 1 : d);
      int s = src[e];
      s = s < 0 ? 0 : (s >= NN ? NN - 1 : s);
      int cb = d >> 8;
      int r = atomicAdd(&lh[cb], 1);
      rk = (((unsigned int)cb) << 13) | (unsigned int)r;
      pv = (((unsigned int)(d & 255)) << 17) | (unsigned int)s;
    }
    sRank[idx] = rk;
    sPay[idx]  = pv;
  }
  __syncthreads();
  // one global atomic per touched (block, bucket)
  for (int i = t; i < NCB; i += SCT) {
    int c = lh[i];
    int g = c ? atomicAdd(&ccur[i], c) : 0;
    lh[i] = cboff[i] + g;       // repurpose as run base
  }
  __syncthreads();
  #pragma unroll
  for (int i = 0; i < EB / SCT; i++) {
    int idx = i * SCT + t;
    unsigned int rk = sRank[idx];
    if (rk != 0xFFFFFFFFu) {
      int cb = rk >> 13;
      int r  = rk & 0x1FFF;
      ebuf[lh[cb] + r] = sPay[idx];
    }
  }
}

// D: per-coarse-bucket refine -> exact CSR + csroff + invd
__global__ __launch_bounds__(256) void k_crefine(
    const unsigned int* __restrict__ ebuf, const int* __restrict__ cboff,
    int* __restrict__ csroff, float* __restrict__ invd,
    int* __restrict__ csrsrc) {
  __shared__ int lh[256], pos[256], cur[256];
  int b = blockIdx.x, t = threadIdx.x;
  lh[t] = 0; cur[t] = 0;
  __syncthreads();
  int beg = cboff[b], end = cboff[b + 1];
  for (int i = beg + t; i < end; i += 256) atomicAdd(&lh[ebuf[i] >> 17], 1);
  __syncthreads();
  int v = lh[t];
  pos[t] = v;
  __syncthreads();
  for (int st = 1; st < 256; st <<= 1) {
    int x = (t >= st) ? pos[t - st] : 0;
    __syncthreads();
    pos[t] += x;
    __syncthreads();
  }
  int nid = b * 256 + t;
  int mybase = cboff[b] + pos[t] - v;
  if (nid < NN) {
    csroff[nid] = mybase;
    invd[nid] = 1.0f / (float)(v < 1 ? 1 : v);
  }
  __syncthreads();
  pos[t] = mybase;
  __syncthreads();
  for (int i = beg + t; i < end; i += 256) {
    unsigned int u = ebuf[i];
    int local = u >> 17;
    int r = atomicAdd(&cur[local], 1);
    csrsrc[pos[local] + r] = (int)(u & 0x1FFFFu);
  }
}

// ---------------- merged weight prep: all 3 layers in one dispatch ----------------
__global__ void k_wprep(const float* __restrict__ Wl0, const float* __restrict__ Wr0,
                        const float* __restrict__ Wl1, const float* __restrict__ Wr1,
                        const float* __restrict__ Wl2, const float* __restrict__ Wr2,
                        unsigned short* __restrict__ B0,
                        unsigned short* __restrict__ B1,
                        unsigned short* __restrict__ B2) {
  int idx = blockIdx.x * 256 + threadIdx.x;
  // B0/B1: 256 rows x 128 k ; B2: 64 rows x 128 k
  if (idx < 32768) {
    int n = idx >> 7, k = idx & 127;
    float v = (n < 128) ? Wl0[k * 128 + n] : Wr0[k * 128 + (n - 128)];
    B0[idx] = f2bf(v);
  } else if (idx < 65536) {
    int j = idx - 32768;
    int n = j >> 7, k = j & 127;
    float v = (n < 128) ? Wl1[k * 128 + n] : Wr1[k * 128 + (n - 128)];
    B1[j] = f2bf(v);
  } else if (idx < 73728) {
    int j = idx - 65536;
    int n = j >> 7, k = j & 127;
    float v = (n < 32) ? Wl2[k * 32 + n] : Wr2[k * 32 + (n - 32)];
    B2[j] = f2bf(v);
  }
}

// ---------------- MFMA GEMM (round-5 structure, unchanged) ----------------
template <int NC, int AFP32>
__global__ __launch_bounds__(512) void k_mgemm(
    const void* __restrict__ Ap, const unsigned short* __restrict__ Bp,
    const float* __restrict__ bias,
    unsigned short* __restrict__ yl, unsigned short* __restrict__ yr) {
  __shared__ unsigned short sA[128 * 136];
  __shared__ unsigned short sB[NC * 136];
  int tid = threadIdx.x;
  int nb  = blockIdx.x * 128;

  if (AFP32) {
    const float* A = (const float*)Ap;
    #pragma unroll
    for (int i = 0; i < 8; i++) {
      int j = i * 512 + tid;
      int m = j >> 5;
      int k4 = (j & 31) * 4;
      int gn = nb + m;
      float4 v = make_float4(0.f, 0.f, 0.f, 0.f);
      if (gn < NN) v = *(const float4*)&A[gn * 128 + k4];
      unsigned int p0 = (unsigned int)f2bf(v.x) | ((unsigned int)f2bf(v.y) << 16);
      unsigned int p1 = (unsigned int)f2bf(v.z) | ((unsigned int)f2bf(v.w) << 16);
      *(uint2*)&sA[m * 136 + k4] = make_uint2(p0, p1);
    }
  } else {
    const unsigned short* A = (const unsigned short*)Ap;
    #pragma unroll
    for (int i = 0; i < 4; i++) {
      int j = i * 512 + tid;
      int m = j >> 4;
      int k8 = (j & 15) * 8;
      int gn = nb + m;
      uint4 v = make_uint4(0, 0, 0, 0);
      if (gn < NN) v = *(const uint4*)&A[gn * 128 + k8];
      *(uint4*)&sA[m * 136 + k8] = v;
    }
  }
  {
    int nchunks = NC * 16;
    for (int j = tid; j < nchunks; j += 512) {
      int n = j >> 4;
      int k8 = (j & 15) * 8;
      *(uint4*)&sB[n * 136 + k8] = *(const uint4*)&Bp[n * 128 + k8];
    }
  }
  __syncthreads();

  int wave = tid >> 6, lane = tid & 63;
  int l15 = lane & 15, lq = lane >> 4;
  constexpr int MT = (NC == 256) ? 4 : 2;
  constexpr int NT = (NC == 256) ? 4 : 2;
  int wm, wn;
  if (NC == 256) { wm = wave & 1; wn = wave >> 1; }
  else           { wm = wave >> 1; wn = wave & 1; }
  int mbase = wm * (MT * 16);
  int nbase = wn * (NT * 16);

  f32x4 acc[MT][NT];
  #pragma unroll
  for (int mi = 0; mi < MT; mi++)
    #pragma unroll
    for (int ni = 0; ni < NT; ni++) acc[mi][ni] = (f32x4){0.f, 0.f, 0.f, 0.f};

  #pragma unroll
  for (int kc = 0; kc < 4; kc++) {
    int k0 = kc * 32 + lq * 8;
    short8 af[MT], bfr[NT];
    #pragma unroll
    for (int mi = 0; mi < MT; mi++)
      af[mi] = *(const short8*)&sA[(mbase + mi * 16 + l15) * 136 + k0];
    #pragma unroll
    for (int ni = 0; ni < NT; ni++)
      bfr[ni] = *(const short8*)&sB[(nbase + ni * 16 + l15) * 136 + k0];
    #pragma unroll
    for (int mi = 0; mi < MT; mi++)
      #pragma unroll
      for (int ni = 0; ni < NT; ni++)
        acc[mi][ni] = __builtin_amdgcn_mfma_f32_16x16x32_bf16(
            af[mi], bfr[ni], acc[mi][ni], 0, 0, 0);
  }

  constexpr int HC = NC / 2;
  #pragma unroll
  for (int mi = 0; mi < MT; mi++) {
    #pragma unroll
    for (int ni = 0; ni < NT; ni++) {
      int n = nbase + ni * 16 + l15;
      #pragma unroll
      for (int r = 0; r < 4; r++) {
        int gn = nb + mbase + mi * 16 + lq * 4 + r;
        if (gn < NN) {
          float v = acc[mi][ni][r];
          if (n < HC) {
            yl[(size_t)gn * HC + n] = f2bf(v);
          } else {
            int n2 = n - HC;
            yr[(size_t)gn * HC + n2] = f2bf(v + bias[n2]);
          }
        }
      }
    }
  }
}

// ---------------- pull aggregation, 128-dim (bf16 gather, 16-deep unroll) ----------------
__global__ __launch_bounds__(256) void k_agg128(
    const unsigned short* __restrict__ yl, const unsigned short* __restrict__ yr,
    const int* __restrict__ off, const int* __restrict__ csr,
    const float* __restrict__ invd, unsigned short* __restrict__ out, int relu) {
  int wid  = (blockIdx.x * 256 + threadIdx.x) >> 6;
  int lane = threadIdx.x & 63;
  if (wid >= NN) return;
  int beg = off[wid], end = off[wid + 1];
  const unsigned int* ylp = (const unsigned int*)yl;
  float ax0 = 0.f, ay0 = 0.f, ax1 = 0.f, ay1 = 0.f;
  float ax2 = 0.f, ay2 = 0.f, ax3 = 0.f, ay3 = 0.f;
  int e = beg;
  for (; e + 15 < end; e += 16) {
    int s[16];
    #pragma unroll
    for (int i = 0; i < 16; i++) s[i] = __builtin_nontemporal_load(&csr[e + i]);
    unsigned int u[16];
    #pragma unroll
    for (int i = 0; i < 16; i++) u[i] = ylp[s[i] * 64 + lane];
    #pragma unroll
    for (int i = 0; i < 16; i += 4) {
      ax0 += bflo(u[i + 0]); ay0 += bfhi(u[i + 0]);
      ax1 += bflo(u[i + 1]); ay1 += bfhi(u[i + 1]);
      ax2 += bflo(u[i + 2]); ay2 += bfhi(u[i + 2]);
      ax3 += bflo(u[i + 3]); ay3 += bfhi(u[i + 3]);
    }
  }
  for (; e + 7 < end; e += 8) {
    int s[8];
    #pragma unroll
    for (int i = 0; i < 8; i++) s[i] = __builtin_nontemporal_load(&csr[e + i]);
    unsigned int u[8];
    #pragma unroll
    for (int i = 0; i < 8; i++) u[i] = ylp[s[i] * 64 + lane];
    #pragma unroll
    for (int i = 0; i < 8; i += 4) {
      ax0 += bflo(u[i + 0]); ay0 += bfhi(u[i + 0]);
      ax1 += bflo(u[i + 1]); ay1 += bfhi(u[i + 1]);
      ax2 += bflo(u[i + 2]); ay2 += bfhi(u[i + 2]);
      ax3 += bflo(u[i + 3]); ay3 += bfhi(u[i + 3]);
    }
  }
  for (; e < end; e++) {
    int s = csr[e];
    unsigned int u = ylp[s * 64 + lane];
    ax0 += bflo(u); ay0 += bfhi(u);
  }
  float sc = invd[wid];
  unsigned int rv = ((const unsigned int*)yr)[wid * 64 + lane];
  float vx = ((ax0 + ax1) + (ax2 + ax3)) * sc + bflo(rv);
  float vy = ((ay0 + ay1) + (ay2 + ay3)) * sc + bfhi(rv);
  if (relu) { vx = fmaxf(vx, 0.f); vy = fmaxf(vy, 0.f); }
  unsigned int ov = (unsigned int)f2bf(vx) | ((unsigned int)f2bf(vy) << 16);
  __builtin_nontemporal_store(ov, &((unsigned int*)out)[wid * 64 + lane]);
}

// ---------------- 32-dim aggregation + log_softmax ----------------
__global__ __launch_bounds__(256) void k_agg32_lsm(
    const unsigned short* __restrict__ yl, const unsigned short* __restrict__ yr,
    const int* __restrict__ off, const int* __restrict__ csr,
    const float* __restrict__ invd, float* __restrict__ out) {
  int row  = (blockIdx.x * 256 + threadIdx.x) >> 5;
  int lane = threadIdx.x & 31;
  if (row >= NN) return;
  int beg = off[row], end = off[row + 1];
  float a0 = 0.f, a1 = 0.f, a2 = 0.f, a3 = 0.f;
  int e = beg;
  for (; e + 7 < end; e += 8) {
    int s[8];
    #pragma unroll
    for (int i = 0; i < 8; i++) s[i] = __builtin_nontemporal_load(&csr[e + i]);
    a0 += bf1(yl[s[0] * 32 + lane]) + bf1(yl[s[4] * 32 + lane]);
    a1 += bf1(yl[s[1] * 32 + lane]) + bf1(yl[s[5] * 32 + lane]);
    a2 += bf1(yl[s[2] * 32 + lane]) + bf1(yl[s[6] * 32 + lane]);
    a3 += bf1(yl[s[3] * 32 + lane]) + bf1(yl[s[7] * 32 + lane]);
  }
  for (; e < end; e++) a0 += bf1(yl[csr[e] * 32 + lane]);
  float v = ((a0 + a1) + (a2 + a3)) * invd[row] + bf1(yr[row * 32 + lane]);
  float m = v;
  #pragma unroll
  for (int o = 16; o; o >>= 1) m = fmaxf(m, __shfl_xor(m, o, 32));
  float ex = expf(v - m);
  float s = ex;
  #pragma unroll
  for (int o = 16; o; o >>= 1) s += __shfl_xor(s, o, 32);
  __builtin_nontemporal_store(v - m - logf(s), &out[row * 32 + lane]);
}

// ---------------- launch ----------------

extern "C" void kernel_launch(void* const* d_in, const int* in_sizes, int n_in,
                              void* d_out, int out_size, void* d_ws, size_t ws_size,
                              hipStream_t stream) {
  (void)in_sizes; (void)n_in; (void)out_size; (void)ws_size;
  const float* x   = (const float*)d_in[0];
  const int*   ei  = (const int*)d_in[1];
  const float* Wl0 = (const float*)d_in[2];
  const float* bl0 = (const float*)d_in[3];
  const float* Wr0 = (const float*)d_in[4];
  const float* Wl1 = (const float*)d_in[5];
  const float* bl1 = (const float*)d_in[6];
  const float* Wr1 = (const float*)d_in[7];
  const float* Wl2 = (const float*)d_in[8];
  const float* bl2 = (const float*)d_in[9];
  const float* Wr2 = (const float*)d_in[10];
  const int* srcI = ei;
  const int* dstI = ei + NE;

  char* w = (char*)d_ws;
  int*   ccur   = (int*)(w + (16 << 10));                       // 391
  int*   cboff  = (int*)(w + (32 << 10));                       // 392
  unsigned short* B0 = (unsigned short*)(w + (64 << 10));       // 64 KB
  unsigned short* B1 = (unsigned short*)(w + (160 << 10));      // 64 KB
  unsigned short* B2 = (unsigned short*)(w + (256 << 10));      // 16 KB
  int*   part   = (int*)(w + (288 << 10));                      // 128*391 = 200 KB
  int*   csroff = (int*)(w + (512 << 10));                      // 400 KB
  float* invd   = (float*)(w + (1024 << 10));                   // 400 KB
  unsigned int* ebuf = (unsigned int*)(w + (size_t)(2) * 1024 * 1024);   // 6.4 MB
  int*   csrsrc = (int*)(w + (size_t)(9) * 1024 * 1024);                 // 6.4 MB
  unsigned short* ylb = (unsigned short*)(w + (size_t)(16) * 1024 * 1024); // 25.6 MB
  unsigned short* yrb = (unsigned short*)(w + (size_t)(48) * 1024 * 1024); // 25.6 MB
  unsigned short* hb  = (unsigned short*)(w + (size_t)(80) * 1024 * 1024); // 25.6 MB

  // CSR build (no memsets needed: part fully written, ccur zeroed in cscan)
  k_chist<<<HBK, 512, 0, stream>>>(dstI, part);
  k_cscan<<<1, 512, 0, stream>>>(part, cboff, ccur, csroff);
  k_cscatter<<<(NE + EB - 1) / EB, SCT, 0, stream>>>(srcI, dstI, cboff, ccur, ebuf);
  k_crefine<<<NCB, 256, 0, stream>>>(ebuf, cboff, csroff, invd, csrsrc);

  // weight prep (single dispatch)
  k_wprep<<<(73728 + 255) / 256, 256, 0, stream>>>(Wl0, Wr0, Wl1, Wr1, Wl2, Wr2,
                                                   B0, B1, B2);

  dim3 gg((NN + 127) / 128);   // 782
  // layer 0 (A = fp32 x, converted during staging)
  k_mgemm<256, 1><<<gg, 512, 0, stream>>>(x, B0, bl0, ylb, yrb);
  k_agg128<<<(NN * 64) / 256, 256, 0, stream>>>(ylb, yrb, csroff, csrsrc, invd, hb, 1);
  // layer 1 (A = bf16 hb)
  k_mgemm<256, 0><<<gg, 512, 0, stream>>>(hb, B1, bl1, ylb, yrb);
  k_agg128<<<(NN * 64) / 256, 256, 0, stream>>>(ylb, yrb, csroff, csrsrc, invd, hb, 1);
  // layer 2 (transform-first, 32-dim) + fused log_softmax
  k_mgemm<64, 0><<<gg, 512, 0, stream>>>(hb, B2, bl2, ylb, yrb);
  k_agg32_lsm<<<(NN * 32) / 256, 256, 0, stream>>>(ylb, yrb, csroff, csrsrc, invd,
                                                   (float*)d_out);
}

// Round 7
// 461.119 us; speedup vs baseline: 1.0793x; 1.0793x over previous
//
#include <hip/hip_runtime.h>
#include <hip/hip_bf16.h>
#include <math.h>

#define NN 100000
#define NE 1600000

#define NCB 391             // coarse buckets of 256 nodes
#define EB  8192            // edges per scatter block
#define SCT 512             // scatter block threads
#define HBK 128             // histogram blocks

typedef __attribute__((ext_vector_type(8))) short short8;
typedef __attribute__((ext_vector_type(4))) float f32x4;

// ---------- bf16 helpers ----------
__device__ __forceinline__ unsigned short f2bf(float f) {
  union { float f; unsigned int i; } v; v.f = f;
  unsigned int i = v.i;
  unsigned int r = (i + 0x7FFFu + ((i >> 16) & 1u)) >> 16;   // RNE
  return (unsigned short)r;
}
__device__ __forceinline__ float bflo(unsigned int u) {
  union { unsigned int i; float f; } v; v.i = u << 16; return v.f;
}
__device__ __forceinline__ float bfhi(unsigned int u) {
  union { unsigned int i; float f; } v; v.i = u & 0xFFFF0000u; return v.f;
}
__device__ __forceinline__ float bf1(unsigned short u) {
  union { unsigned int i; float f; } v; v.i = ((unsigned int)u) << 16; return v.f;
}

// ---------------- CSR build: hierarchical counting sort ----------------
__global__ __launch_bounds__(512) void k_chist(const int* __restrict__ dst,
                                               int* __restrict__ part) {
  __shared__ int h[NCB];
  for (int i = threadIdx.x; i < NCB; i += 512) h[i] = 0;
  __syncthreads();
  int stride = HBK * 512;
  for (int e = blockIdx.x * 512 + threadIdx.x; e < NE; e += stride) {
    int d = dst[e];
    d = d < 0 ? 0 : (d >= NN ? NN - 1 : d);
    atomicAdd(&h[d >> 8], 1);
  }
  __syncthreads();
  for (int i = threadIdx.x; i < NCB; i += 512) part[blockIdx.x * NCB + i] = h[i];
}

__global__ __launch_bounds__(512) void k_cscan(const int* __restrict__ part,
                                               int* __restrict__ cboff,
                                               int* __restrict__ ccur,
                                               int* __restrict__ csroff) {
  __shared__ int sd[512];
  int t = threadIdx.x;
  int v = 0;
  if (t < NCB) {
    int s0 = 0, s1 = 0, s2 = 0, s3 = 0;
    #pragma unroll 4
    for (int k = 0; k < HBK; k += 4) {
      s0 += part[(k + 0) * NCB + t];
      s1 += part[(k + 1) * NCB + t];
      s2 += part[(k + 2) * NCB + t];
      s3 += part[(k + 3) * NCB + t];
    }
    v = (s0 + s1) + (s2 + s3);
    ccur[t] = 0;
  }
  sd[t] = v;
  __syncthreads();
  for (int st = 1; st < 512; st <<= 1) {
    int x = (t >= st) ? sd[t - st] : 0;
    __syncthreads();
    sd[t] += x;
    __syncthreads();
  }
  if (t < NCB) cboff[t] = sd[t] - v;
  if (t == NCB - 1) { cboff[NCB] = sd[t]; csroff[NN] = sd[t]; }
}

__global__ __launch_bounds__(SCT) void k_cscatter(
    const int* __restrict__ src, const int* __restrict__ dst,
    const int* __restrict__ cboff, int* __restrict__ ccur,
    unsigned int* __restrict__ ebuf) {
  __shared__ int lh[NCB];
  __shared__ unsigned int sRank[EB];
  __shared__ unsigned int sPay[EB];
  int t = threadIdx.x;
  int base = blockIdx.x * EB;
  for (int i = t; i < NCB; i += SCT) lh[i] = 0;
  __syncthreads();
  #pragma unroll
  for (int i = 0; i < EB / SCT; i++) {
    int idx = i * SCT + t;
    int e = base + idx;
    unsigned int rk = 0xFFFFFFFFu, pv = 0;
    if (e < NE) {
      int d = dst[e];
      d = d < 0 ? 0 : (d >= NN ? NN - 1 : d);
      int s = src[e];
      s = s < 0 ? 0 : (s >= NN ? NN - 1 : s);
      int cb = d >> 8;
      int r = atomicAdd(&lh[cb], 1);
      rk = (((unsigned int)cb) << 13) | (unsigned int)r;
      pv = (((unsigned int)(d & 255)) << 17) | (unsigned int)s;
    }
    sRank[idx] = rk;
    sPay[idx]  = pv;
  }
  __syncthreads();
  for (int i = t; i < NCB; i += SCT) {
    int c = lh[i];
    int g = c ? atomicAdd(&ccur[i], c) : 0;
    lh[i] = cboff[i] + g;
  }
  __syncthreads();
  #pragma unroll
  for (int i = 0; i < EB / SCT; i++) {
    int idx = i * SCT + t;
    unsigned int rk = sRank[idx];
    if (rk != 0xFFFFFFFFu) {
      int cb = rk >> 13;
      int r  = rk & 0x1FFF;
      ebuf[lh[cb] + r] = sPay[idx];
    }
  }
}

__global__ __launch_bounds__(256) void k_crefine(
    const unsigned int* __restrict__ ebuf, const int* __restrict__ cboff,
    int* __restrict__ csroff, float* __restrict__ invd,
    int* __restrict__ csrsrc) {
  __shared__ int lh[256], pos[256], cur[256];
  int b = blockIdx.x, t = threadIdx.x;
  lh[t] = 0; cur[t] = 0;
  __syncthreads();
  int beg = cboff[b], end = cboff[b + 1];
  for (int i = beg + t; i < end; i += 256) atomicAdd(&lh[ebuf[i] >> 17], 1);
  __syncthreads();
  int v = lh[t];
  pos[t] = v;
  __syncthreads();
  for (int st = 1; st < 256; st <<= 1) {
    int x = (t >= st) ? pos[t - st] : 0;
    __syncthreads();
    pos[t] += x;
    __syncthreads();
  }
  int nid = b * 256 + t;
  int mybase = cboff[b] + pos[t] - v;
  if (nid < NN) {
    csroff[nid] = mybase;
    invd[nid] = 1.0f / (float)(v < 1 ? 1 : v);
  }
  __syncthreads();
  pos[t] = mybase;
  __syncthreads();
  for (int i = beg + t; i < end; i += 256) {
    unsigned int u = ebuf[i];
    int local = u >> 17;
    int r = atomicAdd(&cur[local], 1);
    csrsrc[pos[local] + r] = (int)(u & 0x1FFFFu);
  }
}

// ---------------- merged weight prep ----------------
__global__ void k_wprep(const float* __restrict__ Wl0, const float* __restrict__ Wr0,
                        const float* __restrict__ Wl1, const float* __restrict__ Wr1,
                        const float* __restrict__ Wl2, const float* __restrict__ Wr2,
                        unsigned short* __restrict__ B0,
                        unsigned short* __restrict__ B1,
                        unsigned short* __restrict__ B2) {
  int idx = blockIdx.x * 256 + threadIdx.x;
  if (idx < 32768) {
    int n = idx >> 7, k = idx & 127;
    float v = (n < 128) ? Wl0[k * 128 + n] : Wr0[k * 128 + (n - 128)];
    B0[idx] = f2bf(v);
  } else if (idx < 65536) {
    int j = idx - 32768;
    int n = j >> 7, k = j & 127;
    float v = (n < 128) ? Wl1[k * 128 + n] : Wr1[k * 128 + (n - 128)];
    B1[j] = f2bf(v);
  } else if (idx < 73728) {
    int j = idx - 65536;
    int n = j >> 7, k = j & 127;
    float v = (n < 32) ? Wl2[k * 32 + n] : Wr2[k * 32 + (n - 32)];
    B2[j] = f2bf(v);
  }
}

// ---------------- MFMA GEMM: A staged in LDS; B read directly from global ----
// B is one 64 KB weight matrix shared by ALL blocks -> L2-resident; reading
// its fragments straight from global removes 70 KB of LDS, lifting occupancy
// from 1 block/CU to 3-4 (the round-6 version was staging-serialized).
template <int NC, int AFP32>
__global__ __launch_bounds__(512) void k_mgemm(
    const void* __restrict__ Ap, const unsigned short* __restrict__ Bp,
    const float* __restrict__ bias,
    unsigned short* __restrict__ yl, unsigned short* __restrict__ yr) {
  __shared__ unsigned short sA[128 * 136];   // 34.8 KB
  int tid = threadIdx.x;
  int nb  = blockIdx.x * 128;

  if (AFP32) {
    const float* A = (const float*)Ap;
    #pragma unroll
    for (int i = 0; i < 8; i++) {
      int j = i * 512 + tid;
      int m = j >> 5;
      int k4 = (j & 31) * 4;
      int gn = nb + m;
      float4 v = make_float4(0.f, 0.f, 0.f, 0.f);
      if (gn < NN) v = *(const float4*)&A[gn * 128 + k4];
      unsigned int p0 = (unsigned int)f2bf(v.x) | ((unsigned int)f2bf(v.y) << 16);
      unsigned int p1 = (unsigned int)f2bf(v.z) | ((unsigned int)f2bf(v.w) << 16);
      *(uint2*)&sA[m * 136 + k4] = make_uint2(p0, p1);
    }
  } else {
    const unsigned short* A = (const unsigned short*)Ap;
    #pragma unroll
    for (int i = 0; i < 4; i++) {
      int j = i * 512 + tid;
      int m = j >> 4;
      int k8 = (j & 15) * 8;
      int gn = nb + m;
      uint4 v = make_uint4(0, 0, 0, 0);
      if (gn < NN) v = *(const uint4*)&A[gn * 128 + k8];
      *(uint4*)&sA[m * 136 + k8] = v;
    }
  }
  __syncthreads();

  int wave = tid >> 6, lane = tid & 63;
  int l15 = lane & 15, lq = lane >> 4;
  constexpr int MT = (NC == 256) ? 4 : 2;
  constexpr int NT = (NC == 256) ? 4 : 2;
  int wm, wn;
  if (NC == 256) { wm = wave & 1; wn = wave >> 1; }
  else           { wm = wave >> 1; wn = wave & 1; }
  int mbase = wm * (MT * 16);
  int nbase = wn * (NT * 16);

  f32x4 acc[MT][NT];
  #pragma unroll
  for (int mi = 0; mi < MT; mi++)
    #pragma unroll
    for (int ni = 0; ni < NT; ni++) acc[mi][ni] = (f32x4){0.f, 0.f, 0.f, 0.f};

  #pragma unroll
  for (int kc = 0; kc < 4; kc++) {
    int k0 = kc * 32 + lq * 8;
    short8 af[MT], bfr[NT];
    #pragma unroll
    for (int ni = 0; ni < NT; ni++)
      bfr[ni] = *(const short8*)&Bp[(nbase + ni * 16 + l15) * 128 + k0];
    #pragma unroll
    for (int mi = 0; mi < MT; mi++)
      af[mi] = *(const short8*)&sA[(mbase + mi * 16 + l15) * 136 + k0];
    #pragma unroll
    for (int mi = 0; mi < MT; mi++)
      #pragma unroll
      for (int ni = 0; ni < NT; ni++)
        acc[mi][ni] = __builtin_amdgcn_mfma_f32_16x16x32_bf16(
            af[mi], bfr[ni], acc[mi][ni], 0, 0, 0);
  }

  constexpr int HC = NC / 2;
  #pragma unroll
  for (int mi = 0; mi < MT; mi++) {
    #pragma unroll
    for (int ni = 0; ni < NT; ni++) {
      int n = nbase + ni * 16 + l15;
      #pragma unroll
      for (int r = 0; r < 4; r++) {
        int gn = nb + mbase + mi * 16 + lq * 4 + r;
        if (gn < NN) {
          float v = acc[mi][ni][r];
          if (n < HC) {
            yl[(size_t)gn * HC + n] = f2bf(v);
          } else {
            int n2 = n - HC;
            yr[(size_t)gn * HC + n2] = f2bf(v + bias[n2]);
          }
        }
      }
    }
  }
}

// ---------------- pull aggregation, 128-dim (round-5 body: 8-deep, plain loads) ----
__global__ __launch_bounds__(256) void k_agg128(
    const unsigned short* __restrict__ yl, const unsigned short* __restrict__ yr,
    const int* __restrict__ off, const int* __restrict__ csr,
    const float* __restrict__ invd, unsigned short* __restrict__ out, int relu) {
  int wid  = (blockIdx.x * 256 + threadIdx.x) >> 6;
  int lane = threadIdx.x & 63;
  if (wid >= NN) return;
  int beg = off[wid], end = off[wid + 1];
  const unsigned int* ylp = (const unsigned int*)yl;
  float ax0 = 0.f, ay0 = 0.f, ax1 = 0.f, ay1 = 0.f;
  float ax2 = 0.f, ay2 = 0.f, ax3 = 0.f, ay3 = 0.f;
  int e = beg;
  for (; e + 7 < end; e += 8) {
    int s0 = csr[e],     s1 = csr[e + 1], s2 = csr[e + 2], s3 = csr[e + 3];
    int s4 = csr[e + 4], s5 = csr[e + 5], s6 = csr[e + 6], s7 = csr[e + 7];
    unsigned int u0 = ylp[s0 * 64 + lane];
    unsigned int u1 = ylp[s1 * 64 + lane];
    unsigned int u2 = ylp[s2 * 64 + lane];
    unsigned int u3 = ylp[s3 * 64 + lane];
    unsigned int u4 = ylp[s4 * 64 + lane];
    unsigned int u5 = ylp[s5 * 64 + lane];
    unsigned int u6 = ylp[s6 * 64 + lane];
    unsigned int u7 = ylp[s7 * 64 + lane];
    ax0 += bflo(u0); ay0 += bfhi(u0);
    ax1 += bflo(u1); ay1 += bfhi(u1);
    ax2 += bflo(u2); ay2 += bfhi(u2);
    ax3 += bflo(u3); ay3 += bfhi(u3);
    ax0 += bflo(u4); ay0 += bfhi(u4);
    ax1 += bflo(u5); ay1 += bfhi(u5);
    ax2 += bflo(u6); ay2 += bfhi(u6);
    ax3 += bflo(u7); ay3 += bfhi(u7);
  }
  for (; e < end; e++) {
    int s = csr[e];
    unsigned int u = ylp[s * 64 + lane];
    ax0 += bflo(u); ay0 += bfhi(u);
  }
  float sc = invd[wid];
  unsigned int rv = ((const unsigned int*)yr)[wid * 64 + lane];
  float vx = ((ax0 + ax1) + (ax2 + ax3)) * sc + bflo(rv);
  float vy = ((ay0 + ay1) + (ay2 + ay3)) * sc + bfhi(rv);
  if (relu) { vx = fmaxf(vx, 0.f); vy = fmaxf(vy, 0.f); }
  ((unsigned int*)out)[wid * 64 + lane] =
      (unsigned int)f2bf(vx) | ((unsigned int)f2bf(vy) << 16);
}

// ---------------- 32-dim aggregation + log_softmax (round-5 body) ----------------
__global__ __launch_bounds__(256) void k_agg32_lsm(
    const unsigned short* __restrict__ yl, const unsigned short* __restrict__ yr,
    const int* __restrict__ off, const int* __restrict__ csr,
    const float* __restrict__ invd, float* __restrict__ out) {
  int row  = (blockIdx.x * 256 + threadIdx.x) >> 5;
  int lane = threadIdx.x & 31;
  if (row >= NN) return;
  int beg = off[row], end = off[row + 1];
  float a0 = 0.f, a1 = 0.f, a2 = 0.f, a3 = 0.f;
  int e = beg;
  for (; e + 3 < end; e += 4) {
    int s0 = csr[e], s1 = csr[e + 1], s2 = csr[e + 2], s3 = csr[e + 3];
    a0 += bf1(yl[s0 * 32 + lane]);
    a1 += bf1(yl[s1 * 32 + lane]);
    a2 += bf1(yl[s2 * 32 + lane]);
    a3 += bf1(yl[s3 * 32 + lane]);
  }
  for (; e < end; e++) a0 += bf1(yl[csr[e] * 32 + lane]);
  float v = ((a0 + a1) + (a2 + a3)) * invd[row] + bf1(yr[row * 32 + lane]);
  float m = v;
  #pragma unroll
  for (int o = 16; o; o >>= 1) m = fmaxf(m, __shfl_xor(m, o, 32));
  float ex = expf(v - m);
  float s = ex;
  #pragma unroll
  for (int o = 16; o; o >>= 1) s += __shfl_xor(s, o, 32);
  out[row * 32 + lane] = v - m - logf(s);
}

// ---------------- launch ----------------

extern "C" void kernel_launch(void* const* d_in, const int* in_sizes, int n_in,
                              void* d_out, int out_size, void* d_ws, size_t ws_size,
                              hipStream_t stream) {
  (void)in_sizes; (void)n_in; (void)out_size; (void)ws_size;
  const float* x   = (const float*)d_in[0];
  const int*   ei  = (const int*)d_in[1];
  const float* Wl0 = (const float*)d_in[2];
  const float* bl0 = (const float*)d_in[3];
  const float* Wr0 = (const float*)d_in[4];
  const float* Wl1 = (const float*)d_in[5];
  const float* bl1 = (const float*)d_in[6];
  const float* Wr1 = (const float*)d_in[7];
  const float* Wl2 = (const float*)d_in[8];
  const float* bl2 = (const float*)d_in[9];
  const float* Wr2 = (const float*)d_in[10];
  const int* srcI = ei;
  const int* dstI = ei + NE;

  char* w = (char*)d_ws;
  int*   ccur   = (int*)(w + (16 << 10));                       // 391
  int*   cboff  = (int*)(w + (32 << 10));                       // 392
  unsigned short* B0 = (unsigned short*)(w + (64 << 10));       // 64 KB
  unsigned short* B1 = (unsigned short*)(w + (160 << 10));      // 64 KB
  unsigned short* B2 = (unsigned short*)(w + (256 << 10));      // 16 KB
  int*   part   = (int*)(w + (288 << 10));                      // 200 KB
  int*   csroff = (int*)(w + (512 << 10));                      // 400 KB
  float* invd   = (float*)(w + (1024 << 10));                   // 400 KB
  unsigned int* ebuf = (unsigned int*)(w + (size_t)(2) * 1024 * 1024);   // 6.4 MB
  int*   csrsrc = (int*)(w + (size_t)(9) * 1024 * 1024);                 // 6.4 MB
  unsigned short* ylb = (unsigned short*)(w + (size_t)(16) * 1024 * 1024); // 25.6 MB
  unsigned short* yrb = (unsigned short*)(w + (size_t)(48) * 1024 * 1024); // 25.6 MB
  unsigned short* hb  = (unsigned short*)(w + (size_t)(80) * 1024 * 1024); // 25.6 MB

  // CSR build
  k_chist<<<HBK, 512, 0, stream>>>(dstI, part);
  k_cscan<<<1, 512, 0, stream>>>(part, cboff, ccur, csroff);
  k_cscatter<<<(NE + EB - 1) / EB, SCT, 0, stream>>>(srcI, dstI, cboff, ccur, ebuf);
  k_crefine<<<NCB, 256, 0, stream>>>(ebuf, cboff, csroff, invd, csrsrc);

  // weight prep
  k_wprep<<<(73728 + 255) / 256, 256, 0, stream>>>(Wl0, Wr0, Wl1, Wr1, Wl2, Wr2,
                                                   B0, B1, B2);

  dim3 gg((NN + 127) / 128);   // 782
  // layer 0 (A = fp32 x, converted during staging)
  k_mgemm<256, 1><<<gg, 512, 0, stream>>>(x, B0, bl0, ylb, yrb);
  k_agg128<<<(NN * 64) / 256, 256, 0, stream>>>(ylb, yrb, csroff, csrsrc, invd, hb, 1);
  // layer 1 (A = bf16 hb)
  k_mgemm<256, 0><<<gg, 512, 0, stream>>>(hb, B1, bl1, ylb, yrb);
  k_agg128<<<(NN * 64) / 256, 256, 0, stream>>>(ylb, yrb, csroff, csrsrc, invd, hb, 1);
  // layer 2 (transform-first, 32-dim) + fused log_softmax
  k_mgemm<64, 0><<<gg, 512, 0, stream>>>(hb, B2, bl2, ylb, yrb);
  k_agg32_lsm<<<(NN * 32) / 256, 256, 0, stream>>>(ylb, yrb, csroff, csrsrc, invd,
                                                   (float*)d_out);
}

// Round 8
// 450.694 us; speedup vs baseline: 1.1043x; 1.0231x over previous
//
#include <hip/hip_runtime.h>
#include <hip/hip_bf16.h>
#include <math.h>

#define NN 100000
#define NE 1600000

#define NCB 391             // coarse buckets of 256 nodes
#define EB  8192            // edges per scatter block
#define SCT 512             // scatter block threads
#define HBK 64              // histogram blocks
#define NSB 196             // scatter blocks = ceil(NE/EB)
#define WPB 144             // wprep blocks (73728/512)

typedef __attribute__((ext_vector_type(8))) short short8;
typedef __attribute__((ext_vector_type(4))) float f32x4;

// ---------- bf16 helpers ----------
__device__ __forceinline__ unsigned short f2bf(float f) {
  union { float f; unsigned int i; } v; v.f = f;
  unsigned int i = v.i;
  unsigned int r = (i + 0x7FFFu + ((i >> 16) & 1u)) >> 16;   // RNE
  return (unsigned short)r;
}
__device__ __forceinline__ float bflo(unsigned int u) {
  union { unsigned int i; float f; } v; v.i = u << 16; return v.f;
}
__device__ __forceinline__ float bfhi(unsigned int u) {
  union { unsigned int i; float f; } v; v.i = u & 0xFFFF0000u; return v.f;
}
__device__ __forceinline__ float bf1(unsigned short u) {
  union { unsigned int i; float f; } v; v.i = ((unsigned int)u) << 16; return v.f;
}

// ---------------- fused prep: bucket histogram (blocks 0..HBK-1) + weight
// prep (blocks HBK..HBK+WPB-1). wprep is CSR-independent; hide it here. ----
__global__ __launch_bounds__(512) void k_prep(
    const int* __restrict__ dst, int* __restrict__ part,
    const float* __restrict__ Wl0, const float* __restrict__ Wr0,
    const float* __restrict__ Wl1, const float* __restrict__ Wr1,
    const float* __restrict__ Wl2, const float* __restrict__ Wr2,
    unsigned short* __restrict__ B0, unsigned short* __restrict__ B1,
    unsigned short* __restrict__ B2) {
  if (blockIdx.x < HBK) {
    __shared__ int h[NCB];
    for (int i = threadIdx.x; i < NCB; i += 512) h[i] = 0;
    __syncthreads();
    int stride = HBK * 512;
    for (int e = blockIdx.x * 512 + threadIdx.x; e < NE; e += stride) {
      int d = dst[e];
      d = d < 0 ? 0 : (d >= NN ? NN - 1 : d);
      atomicAdd(&h[d >> 8], 1);
    }
    __syncthreads();
    for (int i = threadIdx.x; i < NCB; i += 512) part[blockIdx.x * NCB + i] = h[i];
  } else {
    int idx = (blockIdx.x - HBK) * 512 + threadIdx.x;   // [0, 73728)
    if (idx < 32768) {
      int n = idx >> 7, k = idx & 127;
      float v = (n < 128) ? Wl0[k * 128 + n] : Wr0[k * 128 + (n - 128)];
      B0[idx] = f2bf(v);
    } else if (idx < 65536) {
      int j = idx - 32768;
      int n = j >> 7, k = j & 127;
      float v = (n < 128) ? Wl1[k * 128 + n] : Wr1[k * 128 + (n - 128)];
      B1[j] = f2bf(v);
    } else if (idx < 73728) {
      int j = idx - 65536;
      int n = j >> 7, k = j & 127;
      float v = (n < 32) ? Wl2[k * 32 + n] : Wr2[k * 32 + (n - 32)];
      B2[j] = f2bf(v);
    }
  }
}

// ---------------- scan of coarse counts; zeroes ccur ----------------
__global__ __launch_bounds__(512) void k_cscan(const int* __restrict__ part,
                                               int* __restrict__ cboff,
                                               int* __restrict__ ccur,
                                               int* __restrict__ csroff) {
  __shared__ int sd[512];
  int t = threadIdx.x;
  int v = 0;
  if (t < NCB) {
    int s0 = 0, s1 = 0, s2 = 0, s3 = 0;
    #pragma unroll 4
    for (int k = 0; k < HBK; k += 4) {
      s0 += part[(k + 0) * NCB + t];
      s1 += part[(k + 1) * NCB + t];
      s2 += part[(k + 2) * NCB + t];
      s3 += part[(k + 3) * NCB + t];
    }
    v = (s0 + s1) + (s2 + s3);
    ccur[t] = 0;
  }
  sd[t] = v;
  __syncthreads();
  for (int st = 1; st < 512; st <<= 1) {
    int x = (t >= st) ? sd[t - st] : 0;
    __syncthreads();
    sd[t] += x;
    __syncthreads();
  }
  if (t < NCB) cboff[t] = sd[t] - v;
  if (t == NCB - 1) { cboff[NCB] = sd[t]; csroff[NN] = sd[t]; }
}

// ---------------- fused scatter + layer-0 MFMA GEMM ----------------
// blocks [0,NSB): edge scatter; blocks [NSB, NSB+782): mgemm<256, fp32 A>.
// Independent work co-dispatched to overlap (serial stream can't express it).
// LDS: union of scatter (67.1 KB) and gemm sA (34.8 KB).

__device__ __forceinline__ void cscatter_body(
    char* smem, int bid,
    const int* __restrict__ src, const int* __restrict__ dst,
    const int* __restrict__ cboff, int* __restrict__ ccur,
    unsigned int* __restrict__ ebuf) {
  int* lh = (int*)smem;                                  // NCB ints
  unsigned int* sRank = (unsigned int*)(smem + 1600);    // EB uints
  unsigned int* sPay  = (unsigned int*)(smem + 1600 + EB * 4);
  int t = threadIdx.x;
  int base = bid * EB;
  for (int i = t; i < NCB; i += SCT) lh[i] = 0;
  __syncthreads();
  #pragma unroll
  for (int i = 0; i < EB / SCT; i++) {
    int idx = i * SCT + t;
    int e = base + idx;
    unsigned int rk = 0xFFFFFFFFu, pv = 0;
    if (e < NE) {
      int d = dst[e];
      d = d < 0 ? 0 : (d >= NN ? NN - 1 : d);
      int s = src[e];
      s = s < 0 ? 0 : (s >= NN ? NN - 1 : s);
      int cb = d >> 8;
      int r = atomicAdd(&lh[cb], 1);
      rk = (((unsigned int)cb) << 13) | (unsigned int)r;
      pv = (((unsigned int)(d & 255)) << 17) | (unsigned int)s;
    }
    sRank[idx] = rk;
    sPay[idx]  = pv;
  }
  __syncthreads();
  for (int i = t; i < NCB; i += SCT) {
    int c = lh[i];
    int g = c ? atomicAdd(&ccur[i], c) : 0;
    lh[i] = cboff[i] + g;
  }
  __syncthreads();
  #pragma unroll
  for (int i = 0; i < EB / SCT; i++) {
    int idx = i * SCT + t;
    unsigned int rk = sRank[idx];
    if (rk != 0xFFFFFFFFu) {
      int cb = rk >> 13;
      int r  = rk & 0x1FFF;
      ebuf[lh[cb] + r] = sPay[idx];
    }
  }
}

__device__ __forceinline__ void mgemm0_body(
    char* smem, int bid, const float* __restrict__ A,
    const unsigned short* __restrict__ Bp, const float* __restrict__ bias,
    unsigned short* __restrict__ yl, unsigned short* __restrict__ yr) {
  unsigned short* sA = (unsigned short*)smem;   // 128*136*2 = 34.8 KB
  int tid = threadIdx.x;
  int nb  = bid * 128;

  #pragma unroll
  for (int i = 0; i < 8; i++) {
    int j = i * 512 + tid;
    int m = j >> 5;
    int k4 = (j & 31) * 4;
    int gn = nb + m;
    float4 v = make_float4(0.f, 0.f, 0.f, 0.f);
    if (gn < NN) v = *(const float4*)&A[gn * 128 + k4];
    unsigned int p0 = (unsigned int)f2bf(v.x) | ((unsigned int)f2bf(v.y) << 16);
    unsigned int p1 = (unsigned int)f2bf(v.z) | ((unsigned int)f2bf(v.w) << 16);
    *(uint2*)&sA[m * 136 + k4] = make_uint2(p0, p1);
  }
  __syncthreads();

  int wave = tid >> 6, lane = tid & 63;
  int l15 = lane & 15, lq = lane >> 4;
  int wm = wave & 1, wn = wave >> 1;
  int mbase = wm * 64;
  int nbase = wn * 64;

  f32x4 acc[4][4];
  #pragma unroll
  for (int mi = 0; mi < 4; mi++)
    #pragma unroll
    for (int ni = 0; ni < 4; ni++) acc[mi][ni] = (f32x4){0.f, 0.f, 0.f, 0.f};

  #pragma unroll
  for (int kc = 0; kc < 4; kc++) {
    int k0 = kc * 32 + lq * 8;
    short8 af[4], bfr[4];
    #pragma unroll
    for (int ni = 0; ni < 4; ni++)
      bfr[ni] = *(const short8*)&Bp[(nbase + ni * 16 + l15) * 128 + k0];
    #pragma unroll
    for (int mi = 0; mi < 4; mi++)
      af[mi] = *(const short8*)&sA[(mbase + mi * 16 + l15) * 136 + k0];
    #pragma unroll
    for (int mi = 0; mi < 4; mi++)
      #pragma unroll
      for (int ni = 0; ni < 4; ni++)
        acc[mi][ni] = __builtin_amdgcn_mfma_f32_16x16x32_bf16(
            af[mi], bfr[ni], acc[mi][ni], 0, 0, 0);
  }

  #pragma unroll
  for (int mi = 0; mi < 4; mi++) {
    #pragma unroll
    for (int ni = 0; ni < 4; ni++) {
      int n = nbase + ni * 16 + l15;
      #pragma unroll
      for (int r = 0; r < 4; r++) {
        int gn = nb + mbase + mi * 16 + lq * 4 + r;
        if (gn < NN) {
          float v = acc[mi][ni][r];
          if (n < 128) {
            yl[(size_t)gn * 128 + n] = f2bf(v);
          } else {
            int n2 = n - 128;
            yr[(size_t)gn * 128 + n2] = f2bf(v + bias[n2]);
          }
        }
      }
    }
  }
}

__global__ __launch_bounds__(512) void k_scatgemm(
    const int* __restrict__ src, const int* __restrict__ dst,
    const int* __restrict__ cboff, int* __restrict__ ccur,
    unsigned int* __restrict__ ebuf,
    const float* __restrict__ x, const unsigned short* __restrict__ B0,
    const float* __restrict__ bias,
    unsigned short* __restrict__ yl, unsigned short* __restrict__ yr) {
  __shared__ char smem[1600 + EB * 8];   // 67.1 KB union
  if (blockIdx.x < NSB) {
    cscatter_body(smem, blockIdx.x, src, dst, cboff, ccur, ebuf);
  } else {
    mgemm0_body(smem, blockIdx.x - NSB, x, B0, bias, yl, yr);
  }
}

// ---------------- per-coarse-bucket refine -> exact CSR ----------------
__global__ __launch_bounds__(256) void k_crefine(
    const unsigned int* __restrict__ ebuf, const int* __restrict__ cboff,
    int* __restrict__ csroff, float* __restrict__ invd,
    int* __restrict__ csrsrc) {
  __shared__ int lh[256], pos[256], cur[256];
  int b = blockIdx.x, t = threadIdx.x;
  lh[t] = 0; cur[t] = 0;
  __syncthreads();
  int beg = cboff[b], end = cboff[b + 1];
  for (int i = beg + t; i < end; i += 256) atomicAdd(&lh[ebuf[i] >> 17], 1);
  __syncthreads();
  int v = lh[t];
  pos[t] = v;
  __syncthreads();
  for (int st = 1; st < 256; st <<= 1) {
    int x = (t >= st) ? pos[t - st] : 0;
    __syncthreads();
    pos[t] += x;
    __syncthreads();
  }
  int nid = b * 256 + t;
  int mybase = cboff[b] + pos[t] - v;
  if (nid < NN) {
    csroff[nid] = mybase;
    invd[nid] = 1.0f / (float)(v < 1 ? 1 : v);
  }
  __syncthreads();
  pos[t] = mybase;
  __syncthreads();
  for (int i = beg + t; i < end; i += 256) {
    unsigned int u = ebuf[i];
    int local = u >> 17;
    int r = atomicAdd(&cur[local], 1);
    csrsrc[pos[local] + r] = (int)(u & 0x1FFFFu);
  }
}

// ---------------- standalone MFMA GEMM (layers 1,2; bf16 A) ----------------
template <int NC>
__global__ __launch_bounds__(512) void k_mgemm(
    const unsigned short* __restrict__ A, const unsigned short* __restrict__ Bp,
    const float* __restrict__ bias,
    unsigned short* __restrict__ yl, unsigned short* __restrict__ yr) {
  __shared__ unsigned short sA[128 * 136];
  int tid = threadIdx.x;
  int nb  = blockIdx.x * 128;

  #pragma unroll
  for (int i = 0; i < 4; i++) {
    int j = i * 512 + tid;
    int m = j >> 4;
    int k8 = (j & 15) * 8;
    int gn = nb + m;
    uint4 v = make_uint4(0, 0, 0, 0);
    if (gn < NN) v = *(const uint4*)&A[gn * 128 + k8];
    *(uint4*)&sA[m * 136 + k8] = v;
  }
  __syncthreads();

  int wave = tid >> 6, lane = tid & 63;
  int l15 = lane & 15, lq = lane >> 4;
  constexpr int MT = (NC == 256) ? 4 : 2;
  constexpr int NT = (NC == 256) ? 4 : 2;
  int wm, wn;
  if (NC == 256) { wm = wave & 1; wn = wave >> 1; }
  else           { wm = wave >> 1; wn = wave & 1; }
  int mbase = wm * (MT * 16);
  int nbase = wn * (NT * 16);

  f32x4 acc[MT][NT];
  #pragma unroll
  for (int mi = 0; mi < MT; mi++)
    #pragma unroll
    for (int ni = 0; ni < NT; ni++) acc[mi][ni] = (f32x4){0.f, 0.f, 0.f, 0.f};

  #pragma unroll
  for (int kc = 0; kc < 4; kc++) {
    int k0 = kc * 32 + lq * 8;
    short8 af[MT], bfr[NT];
    #pragma unroll
    for (int ni = 0; ni < NT; ni++)
      bfr[ni] = *(const short8*)&Bp[(nbase + ni * 16 + l15) * 128 + k0];
    #pragma unroll
    for (int mi = 0; mi < MT; mi++)
      af[mi] = *(const short8*)&sA[(mbase + mi * 16 + l15) * 136 + k0];
    #pragma unroll
    for (int mi = 0; mi < MT; mi++)
      #pragma unroll
      for (int ni = 0; ni < NT; ni++)
        acc[mi][ni] = __builtin_amdgcn_mfma_f32_16x16x32_bf16(
            af[mi], bfr[ni], acc[mi][ni], 0, 0, 0);
  }

  constexpr int HC = NC / 2;
  #pragma unroll
  for (int mi = 0; mi < MT; mi++) {
    #pragma unroll
    for (int ni = 0; ni < NT; ni++) {
      int n = nbase + ni * 16 + l15;
      #pragma unroll
      for (int r = 0; r < 4; r++) {
        int gn = nb + mbase + mi * 16 + lq * 4 + r;
        if (gn < NN) {
          float v = acc[mi][ni][r];
          if (n < HC) {
            yl[(size_t)gn * HC + n] = f2bf(v);
          } else {
            int n2 = n - HC;
            yr[(size_t)gn * HC + n2] = f2bf(v + bias[n2]);
          }
        }
      }
    }
  }
}

// ---------------- pull aggregation, 128-dim (proven round-5 body) ----------
__global__ __launch_bounds__(256) void k_agg128(
    const unsigned short* __restrict__ yl, const unsigned short* __restrict__ yr,
    const int* __restrict__ off, const int* __restrict__ csr,
    const float* __restrict__ invd, unsigned short* __restrict__ out, int relu) {
  int wid  = (blockIdx.x * 256 + threadIdx.x) >> 6;
  int lane = threadIdx.x & 63;
  if (wid >= NN) return;
  int beg = off[wid], end = off[wid + 1];
  const unsigned int* ylp = (const unsigned int*)yl;
  float ax0 = 0.f, ay0 = 0.f, ax1 = 0.f, ay1 = 0.f;
  float ax2 = 0.f, ay2 = 0.f, ax3 = 0.f, ay3 = 0.f;
  int e = beg;
  for (; e + 7 < end; e += 8) {
    int s0 = csr[e],     s1 = csr[e + 1], s2 = csr[e + 2], s3 = csr[e + 3];
    int s4 = csr[e + 4], s5 = csr[e + 5], s6 = csr[e + 6], s7 = csr[e + 7];
    unsigned int u0 = ylp[s0 * 64 + lane];
    unsigned int u1 = ylp[s1 * 64 + lane];
    unsigned int u2 = ylp[s2 * 64 + lane];
    unsigned int u3 = ylp[s3 * 64 + lane];
    unsigned int u4 = ylp[s4 * 64 + lane];
    unsigned int u5 = ylp[s5 * 64 + lane];
    unsigned int u6 = ylp[s6 * 64 + lane];
    unsigned int u7 = ylp[s7 * 64 + lane];
    ax0 += bflo(u0); ay0 += bfhi(u0);
    ax1 += bflo(u1); ay1 += bfhi(u1);
    ax2 += bflo(u2); ay2 += bfhi(u2);
    ax3 += bflo(u3); ay3 += bfhi(u3);
    ax0 += bflo(u4); ay0 += bfhi(u4);
    ax1 += bflo(u5); ay1 += bfhi(u5);
    ax2 += bflo(u6); ay2 += bfhi(u6);
    ax3 += bflo(u7); ay3 += bfhi(u7);
  }
  for (; e < end; e++) {
    int s = csr[e];
    unsigned int u = ylp[s * 64 + lane];
    ax0 += bflo(u); ay0 += bfhi(u);
  }
  float sc = invd[wid];
  unsigned int rv = ((const unsigned int*)yr)[wid * 64 + lane];
  float vx = ((ax0 + ax1) + (ax2 + ax3)) * sc + bflo(rv);
  float vy = ((ay0 + ay1) + (ay2 + ay3)) * sc + bfhi(rv);
  if (relu) { vx = fmaxf(vx, 0.f); vy = fmaxf(vy, 0.f); }
  ((unsigned int*)out)[wid * 64 + lane] =
      (unsigned int)f2bf(vx) | ((unsigned int)f2bf(vy) << 16);
}

// ---------------- 32-dim aggregation + log_softmax ----------------
__global__ __launch_bounds__(256) void k_agg32_lsm(
    const unsigned short* __restrict__ yl, const unsigned short* __restrict__ yr,
    const int* __restrict__ off, const int* __restrict__ csr,
    const float* __restrict__ invd, float* __restrict__ out) {
  int row  = (blockIdx.x * 256 + threadIdx.x) >> 5;
  int lane = threadIdx.x & 31;
  if (row >= NN) return;
  int beg = off[row], end = off[row + 1];
  float a0 = 0.f, a1 = 0.f, a2 = 0.f, a3 = 0.f;
  int e = beg;
  for (; e + 3 < end; e += 4) {
    int s0 = csr[e], s1 = csr[e + 1], s2 = csr[e + 2], s3 = csr[e + 3];
    a0 += bf1(yl[s0 * 32 + lane]);
    a1 += bf1(yl[s1 * 32 + lane]);
    a2 += bf1(yl[s2 * 32 + lane]);
    a3 += bf1(yl[s3 * 32 + lane]);
  }
  for (; e < end; e++) a0 += bf1(yl[csr[e] * 32 + lane]);
  float v = ((a0 + a1) + (a2 + a3)) * invd[row] + bf1(yr[row * 32 + lane]);
  float m = v;
  #pragma unroll
  for (int o = 16; o; o >>= 1) m = fmaxf(m, __shfl_xor(m, o, 32));
  float ex = expf(v - m);
  float s = ex;
  #pragma unroll
  for (int o = 16; o; o >>= 1) s += __shfl_xor(s, o, 32);
  out[row * 32 + lane] = v - m - logf(s);
}

// ---------------- launch ----------------

extern "C" void kernel_launch(void* const* d_in, const int* in_sizes, int n_in,
                              void* d_out, int out_size, void* d_ws, size_t ws_size,
                              hipStream_t stream) {
  (void)in_sizes; (void)n_in; (void)out_size; (void)ws_size;
  const float* x   = (const float*)d_in[0];
  const int*   ei  = (const int*)d_in[1];
  const float* Wl0 = (const float*)d_in[2];
  const float* bl0 = (const float*)d_in[3];
  const float* Wr0 = (const float*)d_in[4];
  const float* Wl1 = (const float*)d_in[5];
  const float* bl1 = (const float*)d_in[6];
  const float* Wr1 = (const float*)d_in[7];
  const float* Wl2 = (const float*)d_in[8];
  const float* bl2 = (const float*)d_in[9];
  const float* Wr2 = (const float*)d_in[10];
  const int* srcI = ei;
  const int* dstI = ei + NE;

  char* w = (char*)d_ws;
  int*   ccur   = (int*)(w + (16 << 10));                       // 391
  int*   cboff  = (int*)(w + (32 << 10));                       // 392
  unsigned short* B0 = (unsigned short*)(w + (64 << 10));       // 64 KB
  unsigned short* B1 = (unsigned short*)(w + (160 << 10));      // 64 KB
  unsigned short* B2 = (unsigned short*)(w + (256 << 10));      // 16 KB
  int*   part   = (int*)(w + (288 << 10));                      // 64*391 = 100 KB
  int*   csroff = (int*)(w + (512 << 10));                      // 400 KB
  float* invd   = (float*)(w + (1024 << 10));                   // 400 KB
  unsigned int* ebuf = (unsigned int*)(w + (size_t)(2) * 1024 * 1024);   // 6.4 MB
  int*   csrsrc = (int*)(w + (size_t)(9) * 1024 * 1024);                 // 6.4 MB
  unsigned short* ylb = (unsigned short*)(w + (size_t)(16) * 1024 * 1024); // 25.6 MB
  unsigned short* yrb = (unsigned short*)(w + (size_t)(48) * 1024 * 1024); // 25.6 MB
  unsigned short* hb  = (unsigned short*)(w + (size_t)(80) * 1024 * 1024); // 25.6 MB

  dim3 gg((NN + 127) / 128);   // 782

  // 1: histogram + weight prep (independent work, one dispatch)
  k_prep<<<HBK + WPB, 512, 0, stream>>>(dstI, part, Wl0, Wr0, Wl1, Wr1, Wl2, Wr2,
                                        B0, B1, B2);
  // 2: scan
  k_cscan<<<1, 512, 0, stream>>>(part, cboff, ccur, csroff);
  // 3: edge scatter + layer-0 GEMM (independent, co-dispatched for overlap)
  k_scatgemm<<<NSB + 782, 512, 0, stream>>>(srcI, dstI, cboff, ccur, ebuf,
                                            x, B0, bl0, ylb, yrb);
  // 4: CSR refine
  k_crefine<<<NCB, 256, 0, stream>>>(ebuf, cboff, csroff, invd, csrsrc);
  // 5: layer-0 aggregation
  k_agg128<<<(NN * 64) / 256, 256, 0, stream>>>(ylb, yrb, csroff, csrsrc, invd, hb, 1);
  // 6: layer-1 GEMM
  k_mgemm<256><<<gg, 512, 0, stream>>>(hb, B1, bl1, ylb, yrb);
  // 7: layer-1 aggregation
  k_agg128<<<(NN * 64) / 256, 256, 0, stream>>>(ylb, yrb, csroff, csrsrc, invd, hb, 1);
  // 8: layer-2 GEMM (transform-first, 32-dim)
  k_mgemm<64><<<gg, 512, 0, stream>>>(hb, B2, bl2, ylb, yrb);
  // 9: layer-2 aggregation + log_softmax
  k_agg32_lsm<<<(NN * 32) / 256, 256, 0, stream>>>(ylb, yrb, csroff, csrsrc, invd,
                                                   (float*)d_out);
}